// Round 24
// baseline (294.961 us; speedup 1.0000x reference)
//
#include <hip/hip_runtime.h>

// (min,+) DP via ANTI-DIAGONAL sweep. Local form (exact unroll of the
// reference scan):  V[r][j] = th[r][j] + min3(V[r][j-1], V[r-1][j], V[r-1][j-1]).
// One wave sweeps diagonals d = r+j = 0..510; per step the carried path is
// ONE wave_shr:1 DPP + v_min3 + v_add  (the old per-row 6-DPP scan is gone).
// Block = 1 image, 4 waves, grid=512 (2 blk/CU): wid3 = chain (SIMD3 pairs
// 2 chains), wid0-2 = preps. Preps write softplus(theta) into a diag-major
// LDS ring (64 diag-rows x 256 floats); col j maps to lane j%64, slot j/64
// -> LDS reads AND writes are 2-way bank (free). 32-diag chunks, 16 barriers.
// Invalid cells: stale LDS theta is harmless (blocked at the r=-1 band,
// which gets explicit NULLV: diag d, col d+1 — disjoint from valid writes).
// Cell (0,0) peeled (its left-boundary is 0, not inf).

#define HH 256
#define WW 256
#define DC 32            // diags per chunk
#define RING 64          // LDS ring of diag rows
#define NDIAG 511        // 0..510
#define NCHK 16          // ceil(511/32)
#define NULLV 1e30f

template<int CTRL>
__device__ __forceinline__ float dpp_f(float oldv, float x) {
    return __builtin_bit_cast(float, __builtin_amdgcn_update_dpp(
        __builtin_bit_cast(int, oldv), __builtin_bit_cast(int, x),
        CTRL, 0xF, 0xF, false));
}
#define WSHR1 0x138      // wave_shr:1 (lane0 keeps old)
#define WROR1 0x13C      // wave_ror:1 (lane0 <- lane63)

__device__ __forceinline__ float softplus_f(float x) {
    // inputs ~N(0,1): |x| < ~6, no overflow; log(1+e^x)
    return __logf(1.0f + __expf(x));
}

__global__ __launch_bounds__(256, 2) void dp_kernel(const float* __restrict__ img,
                                                    float* __restrict__ out) {
    const int tid = threadIdx.x;
    const int wid = tid >> 6;      // 0..3; wid3 = chain (SIMD3)
    const int lane = tid & 63;

    __shared__ __align__(16) float sdiag[RING][WW];   // 64 KB

    const float* gimg = img + (size_t)blockIdx.x * HH * WW;

    if (wid == 3) {
        // ---------------- chain wave: diagonal sweep ----------------
        __builtin_amdgcn_s_setprio(1);
        // slot i covers col j = lane + 64*i; state per slot:
        float Vc0 = NULLV, Vc1 = NULLV, Vc2 = NULLV, Vc3 = NULLV;  // V(diag d-1)
        float Lf0 = NULLV, Lf1 = NULLV, Lf2 = NULLV, Lf3 = NULLV;  // left(d-1) = upleft(d)
        float R0 = NULLV, R1 = NULLV, R2 = NULLV;  // ror1 of Vc0..2 (lane63 wrap feed)

        for (int k = 0; k < NCHK; ++k) {
            __syncthreads();                        // chunk k staged
            const int D0 = k * DC;
            const int D1 = (D0 + DC < NDIAG) ? D0 + DC : NDIAG;
            const float* drow = &sdiag[D0 & (RING - 1)][0];
            float t0 = drow[lane], t1 = drow[lane + 64],
                  t2 = drow[lane + 128], t3 = drow[lane + 192];
            for (int d = D0; d < D1; ++d) {
                float u0, u1, u2, u3;
                if (d + 1 < D1) {                   // prefetch next diag's theta
                    const float* nrow = &sdiag[(d + 1) & (RING - 1)][0];
                    u0 = nrow[lane]; u1 = nrow[lane + 64];
                    u2 = nrow[lane + 128]; u3 = nrow[lane + 192];
                }
                // left neighbors: lane l <- l-1; lane0 of slot i <- lane63 of slot i-1
                float L0 = dpp_f<WSHR1>(NULLV, Vc0);   // col -1 = inf
                float L1 = dpp_f<WSHR1>(R0, Vc1);
                float L2 = dpp_f<WSHR1>(R1, Vc2);
                float L3 = dpp_f<WSHR1>(R2, Vc3);
                float n0 = t0 + fminf(fminf(L0, Vc0), Lf0);
                float n1 = t1 + fminf(fminf(L1, Vc1), Lf1);
                float n2 = t2 + fminf(fminf(L2, Vc2), Lf2);
                float n3 = t3 + fminf(fminf(L3, Vc3), Lf3);
                if (d == 0) {                       // peel (0,0): left-boundary is 0
                    n0 = (lane == 0) ? t0 : n0;
                }
                R0 = dpp_f<WROR1>(n0, n0);          // wrap feeds for next step
                R1 = dpp_f<WROR1>(n1, n1);
                R2 = dpp_f<WROR1>(n2, n2);
                Lf0 = L0; Lf1 = L1; Lf2 = L2; Lf3 = L3;
                Vc0 = n0; Vc1 = n1; Vc2 = n2; Vc3 = n3;
                t0 = u0; t1 = u1; t2 = u2; t3 = u3;
            }
        }
        // V[255][255]: d=510, col 255 = lane 63, slot 3
        if (lane == 63) out[blockIdx.x] = Vc3;
    } else {
        // ---------------- prep waves (wid 0,1,2) ----------------
        const int p = wid;
        for (int k = 0; k < NCHK; ++k) {
            const int D0 = k * DC;
            const int D1 = (D0 + DC < NDIAG) ? D0 + DC : NDIAG;
            const int DW = D1 - D0;
            // r = -1 band: diag d, col d+1 gets NULLV (blocks garbage rows <0)
            if (p == 0) {
                int d = D0 + lane;
                if (lane < DW && d <= 254)
                    sdiag[d & (RING - 1)][d + 1] = NULLV;
            }
            // valid cells: rows r in [max(0,D0-255), min(255,D1-1)],
            // cols c in [D0-r, D1-1-r] ∩ [0,256). lane's col: c ≡ lane (mod 64).
            const int rlo = (D0 - 255 > 0) ? D0 - 255 : 0;
            const int rhi = (D1 - 1 < 255) ? D1 - 1 : 255;
            for (int r = rlo + p; r <= rhi; r += 3) {
                const int a = D0 - r;
                const int off = (lane - a) & 63;
                const int c = a + off;
                if (off < DW && (unsigned)c < 256u) {
                    float th = softplus_f(gimg[r * WW + c]);
                    // diag row = (r + c) & 63 = (D0 + off) & 63
                    sdiag[(D0 + off) & (RING - 1)][c] = th;
                }
            }
            __syncthreads();                        // publish chunk k
        }
    }
}

extern "C" void kernel_launch(void* const* d_in, const int* in_sizes, int n_in,
                              void* d_out, int out_size, void* d_ws, size_t ws_size,
                              hipStream_t stream) {
    const float* img = (const float*)d_in[0];
    float* out = (float*)d_out;
    dp_kernel<<<out_size, 256, 0, stream>>>(img, out);
}

// Round 25
// 95.882 us; speedup vs baseline: 3.0763x; 3.0763x over previous
//
#include <hip/hip_runtime.h>

// (min,+) DP via ANTI-DIAGONAL sweep (algorithm verified in R24; this round
// fixes the engineering). V[r][c] = th[r][c] + min3(left, up, upleft).
// Block = 1 image, 4 waves, grid=512 (2 blk/CU): wid3 = chain (SIMD3 pairs
// two blocks' chains), wid0-2 = preps.
// LDS: diag-major ring sdiag[64][256] (64KB). Diag d lives in ring row d&63,
// so ALL FOUR slots of the chain read ring row (d&63) -> one vaddr per
// chunk, compile-time ds_read offsets (full unroll; compiler pipelines).
// Steady step (chunks 8-15): 4 ds_read + 4 shr-DPP + 4 v_min3 + 4 add +
// 3 ror-DPP. Entering steps (chunks 0-7) add per-slot (c>d -> NULLV) clamp,
// which also kills any NaN from uninitialized LDS. Invalid-high cells
// (r>255) are provably never read by valid cells.
// Prep: float4 loads, 7 rows x 9 quads per iteration (14 iters/chunk),
// softplus -> scattered LDS writes (bank-conflict-free: bank = c&31).

#define NULLV 1e30f

template<int CTRL>
__device__ __forceinline__ float dpp_f(float oldv, float x) {
    return __builtin_bit_cast(float, __builtin_amdgcn_update_dpp(
        __builtin_bit_cast(int, oldv), __builtin_bit_cast(int, x),
        CTRL, 0xF, 0xF, false));
}
#define WSHR1 0x138      // wave_shr:1 (invalid lane0 keeps old)
#define WROR1 0x13C      // wave_ror:1

__device__ __forceinline__ float softplus_f(float x) {
    // inputs ~N(0,1): no overflow risk (R24 passed with this form)
    return __logf(1.0f + __expf(x));
}

struct CS {
    float Vc0, Vc1, Vc2, Vc3;   // V on diag d-1
    float Lf0, Lf1, Lf2, Lf3;   // left(d-1) = upleft(d)
    float R0, R1, R2;           // ror1(Vc_i): lane0 wrap feed for slot i+1
};

template<bool CLAMP>
__device__ __forceinline__ void dstep(CS& S, const float* p, int d, int lane) {
    float t0 = p[0], t1 = p[64], t2 = p[128], t3 = p[192];
    float L0 = dpp_f<WSHR1>(NULLV, S.Vc0);
    float L1 = dpp_f<WSHR1>(S.R0, S.Vc1);
    float L2 = dpp_f<WSHR1>(S.R1, S.Vc2);
    float L3 = dpp_f<WSHR1>(S.R2, S.Vc3);
    float n0 = t0 + fminf(fminf(L0, S.Vc0), S.Lf0);
    float n1 = t1 + fminf(fminf(L1, S.Vc1), S.Lf1);
    float n2 = t2 + fminf(fminf(L2, S.Vc2), S.Lf2);
    float n3 = t3 + fminf(fminf(L3, S.Vc3), S.Lf3);
    if (CLAMP) {
        n0 = (lane       > d) ? NULLV : n0;
        n1 = (lane + 64  > d) ? NULLV : n1;
        n2 = (lane + 128 > d) ? NULLV : n2;
        n3 = (lane + 192 > d) ? NULLV : n3;
    }
    S.R0 = dpp_f<WROR1>(n0, n0);
    S.R1 = dpp_f<WROR1>(n1, n1);
    S.R2 = dpp_f<WROR1>(n2, n2);
    S.Lf0 = L0; S.Lf1 = L1; S.Lf2 = L2; S.Lf3 = L3;
    S.Vc0 = n0; S.Vc1 = n1; S.Vc2 = n2; S.Vc3 = n3;
}

template<bool CLAMP, int N>
__device__ __forceinline__ void chunk_steps(CS& S, const float* cb, int D0, int lane) {
#pragma unroll
    for (int dd = 0; dd < N; ++dd)
        dstep<CLAMP>(S, cb + dd * 256, D0 + dd, lane);
}

// prep: stage all valid cells of chunk k (diags [32k, min(32k+32,511)))
__device__ __forceinline__ void stage_chunk(const float* gimg, float* sf,
                                            int k, int p, int lane) {
    if (lane >= 63) return;                      // 63 lanes = 7 rows x 9 quads
    const int D0 = 32 * k;
    const int D1 = (D0 + 32 < 511) ? D0 + 32 : 511;
    const int rlo = (D0 - 255 > 0) ? D0 - 255 : 0;
    const int rhi = (D1 - 1 < 255) ? D1 - 1 : 255;
    const int rsub = lane / 9, csub = lane % 9;
    for (int rb = rlo; rb <= rhi; rb += 21) {    // 3 preps x 7 rows
        const int r = rb + 7 * p + rsub;
        if (r <= rhi) {
            int w0 = D0 - r; w0 = (w0 > 0) ? w0 : 0;
            int w1 = D1 - r; w1 = (w1 < 256) ? w1 : 256;
            const int a0 = w0 & ~3;
            int cb = a0 + 4 * csub; cb = (cb < 252) ? cb : 252;  // clamp: no OOB
            const float4 v = *reinterpret_cast<const float4*>(&gimg[r * 256 + cb]);
            int c;
            c = cb + 0; if (c >= w0 && c < w1) sf[((r + c) & 63) * 256 + c] = softplus_f(v.x);
            c = cb + 1; if (c >= w0 && c < w1) sf[((r + c) & 63) * 256 + c] = softplus_f(v.y);
            c = cb + 2; if (c >= w0 && c < w1) sf[((r + c) & 63) * 256 + c] = softplus_f(v.z);
            c = cb + 3; if (c >= w0 && c < w1) sf[((r + c) & 63) * 256 + c] = softplus_f(v.w);
        }
    }
}

__global__ __launch_bounds__(256, 2) void dp_kernel(const float* __restrict__ img,
                                                    float* __restrict__ out) {
    const int tid = threadIdx.x;
    const int wid = tid >> 6;      // 0..3; wid3 = chain (SIMD3)
    const int lane = tid & 63;

    __shared__ __align__(16) float sdiag[64][256];   // 64 KB ring
    float* sf = &sdiag[0][0];

    const float* gimg = img + (size_t)blockIdx.x * 256 * 256;

    if (wid == 3) {
        // ---------------- chain wave: diagonal sweep ----------------
        __builtin_amdgcn_s_setprio(1);
        CS S;
        S.Vc0 = S.Vc1 = S.Vc2 = S.Vc3 = NULLV;
        S.Lf0 = S.Lf1 = S.Lf2 = S.Lf3 = NULLV;
        S.R0 = S.R1 = S.R2 = NULLV;

        __syncthreads();                         // B0: chunk 0 staged
        {   // chunk 0: peel d=0, then d=1..31 (entering)
            const float* cb = sf + lane;         // ring row 0
            float t00 = cb[0];                   // theta[0][0] at lane 0
            S.Vc0 = (lane == 0) ? t00 : NULLV;
            S.R0  = dpp_f<WROR1>(S.Vc0, S.Vc0);  // lane0 <- lane63 = NULLV
#pragma unroll
            for (int dd = 1; dd < 32; ++dd)
                dstep<true>(S, cb + dd * 256, dd, lane);
        }
        for (int k = 1; k < 8; ++k) {            // entering chunks
            __syncthreads();
            chunk_steps<true, 32>(S, sf + ((32 * k) & 63) * 256 + lane, 32 * k, lane);
        }
        for (int k = 8; k < 15; ++k) {           // steady chunks
            __syncthreads();
            chunk_steps<false, 32>(S, sf + ((32 * k) & 63) * 256 + lane, 32 * k, lane);
        }
        __syncthreads();                         // B15
        chunk_steps<false, 31>(S, sf + ((32 * 15) & 63) * 256 + lane, 480, lane);
        // V[255][255] = slot3 lane63 after d=510
        if (lane == 63) out[blockIdx.x] = S.Vc3;
    } else {
        // ---------------- prep waves (wid 0,1,2) ----------------
        stage_chunk(gimg, sf, 0, wid, lane);
        for (int k = 0; k < 16; ++k) {
            __syncthreads();                     // Bk: chunk k published
            if (k < 15) stage_chunk(gimg, sf, k + 1, wid, lane);
        }
    }
}

extern "C" void kernel_launch(void* const* d_in, const int* in_sizes, int n_in,
                              void* d_out, int out_size, void* d_ws, size_t ws_size,
                              hipStream_t stream) {
    const float* img = (const float*)d_in[0];
    float* out = (float*)d_out;
    dp_kernel<<<out_size, 256, 0, stream>>>(img, out);
}